// Round 2
// baseline (1491.249 us; speedup 1.0000x reference)
//
#include <hip/hip_runtime.h>

typedef short bf16x8 __attribute__((ext_vector_type(8)));
typedef float f32x4 __attribute__((ext_vector_type(4)));
typedef unsigned u32x4 __attribute__((ext_vector_type(4)));
typedef unsigned u32x2 __attribute__((ext_vector_type(2)));

__device__ __forceinline__ unsigned pk2(float a, float b) {
  unsigned ua = __float_as_uint(a), ub = __float_as_uint(b);
  ua = (ua + 0x7FFFu + ((ua >> 16) & 1u)) >> 16;
  ub = (ub + 0x7FFFu + ((ub >> 16) & 1u)) >> 16;
  return (ua & 0xFFFFu) | (ub << 16);
}
__device__ __forceinline__ bf16x8 mkfrag(unsigned a, unsigned b, unsigned c, unsigned d) {
  u32x4 t = {a, b, c, d};
  return __builtin_bit_cast(bf16x8, t);
}
__device__ __forceinline__ float blo(unsigned u) { return __uint_as_float(u << 16); }
__device__ __forceinline__ float bhi(unsigned u) { return __uint_as_float(u & 0xFFFF0000u); }

// fast GELU (tanh form): v * t/(t+1), t = exp(2*(0.79788456*(v+0.044715 v^3)))
__device__ __forceinline__ float gelu_f(float v) {
  float y = 0.7978845608f * v * (1.f + 0.044715f * v * v);
  float e = exp2f(y * 2.8853900818f);   // exp(2y)
  return v * (1.f - __builtin_amdgcn_rcpf(e + 1.f));
}

// Weight fragment buffer layout (bf16 units):
//  attn mats a=0..7 (uWq,uWk,uWv,uWp,mWq,mWk,mWv,mWp): base a*4096, frag (m*2+f)
//  fW1: base 32768, frags (m*2+f), m=0..15
//  fW2: base 49152, frags (m*8+f), m=0..3, f=0..7
// Each frag block: 64 lanes x 8 bf16; element (lane,j) = W[k][n],
//  n = 16*m + (lane&15), k = 32*f + 4*(lane>>4) + (j&3) + 16*(j>>2)
#define OFF_F1 32768
#define OFF_F2 49152

__global__ __launch_bounds__(256) void prep_w(
    const float* __restrict__ uWq, const float* __restrict__ uWk,
    const float* __restrict__ uWv, const float* __restrict__ uWp,
    const float* __restrict__ mWq, const float* __restrict__ mWk,
    const float* __restrict__ mWv, const float* __restrict__ mWp,
    const float* __restrict__ fW1, const float* __restrict__ fW2,
    unsigned short* __restrict__ ws)
{
  int e = blockIdx.x * blockDim.x + threadIdx.x;   // 0..8191
  if (e >= 8192) return;
  int lane = e & 63;
  int fb   = e >> 6;                               // 0..127
  int g = lane >> 4, li = lane & 15;
  unsigned short outv[8];
#pragma unroll
  for (int j = 0; j < 8; ++j) {
    float val;
    if (fb < 64) {
      int a  = fb >> 3;
      int mf = fb & 7;
      int m = mf >> 1, f = mf & 1;
      int k = f*32 + 4*g + (j&3) + 16*(j>>2);
      int n = 16*m + li;
      const float* W =
        (a==0)?uWq:(a==1)?uWk:(a==2)?uWv:(a==3)?uWp:
        (a==4)?mWq:(a==5)?mWk:(a==6)?mWv:mWp;
      if ((a & 3) != 3) val = W[(n>>3)*512 + k*8 + (n&7)];   // [H,D,HS]
      else              val = W[k*64 + n];                   // [D,D]
    } else if (fb < 96) {
      int mf = fb - 64;
      int m = mf >> 1, f = mf & 1;
      int k = f*32 + 4*g + (j&3) + 16*(j>>2);
      int n = 16*m + li;
      val = fW1[k*256 + n];                                  // [64,256]
    } else {
      int mf = fb - 96;
      int m = mf >> 3, f = mf & 7;
      int k = f*32 + 4*g + (j&3) + 16*(j>>2);
      int n = 16*m + li;
      val = fW2[k*64 + n];                                   // [256,64]
    }
    unsigned u = __float_as_uint(val);
    u = (u + 0x7FFFu + ((u >> 16) & 1u)) >> 16;
    outv[j] = (unsigned short)u;
  }
#pragma unroll
  for (int j = 0; j < 8; ++j) ws[(long)e*8 + j] = outv[j];
}

#define NU 36   // u32 per K/V LDS row (32 data + 4 pad)

__global__ __launch_bounds__(64, 2) void tblock_kern(
    const float* __restrict__ x,
    const float* __restrict__ ubq, const float* __restrict__ ubk,
    const float* __restrict__ ubv, const float* __restrict__ ubp,
    const float* __restrict__ mbq, const float* __restrict__ mbk,
    const float* __restrict__ mbv, const float* __restrict__ mbp,
    const float* __restrict__ fb1, const float* __restrict__ fb2,
    const float* __restrict__ g1, const float* __restrict__ be1,
    const float* __restrict__ g2, const float* __restrict__ be2,
    const unsigned short* __restrict__ wf,
    float* __restrict__ outp)
{
  __shared__ unsigned KS[2][16][NU];   // bf16-packed K (with bias), 4.5 KB
  __shared__ unsigned VS[2][16][NU];   // bf16-packed V (with bias), 4.5 KB

  const int lane = threadIdx.x;
  const int t = lane & 15, g = lane >> 4;
  const long sbase = (long)blockIdx.x * 2048;   // 2 seqs * 1024 elems

  f32x4 R[2][4];
#pragma unroll
  for (int s = 0; s < 2; ++s)
#pragma unroll
    for (int m = 0; m < 4; ++m)
      R[s][m] = *(const f32x4*)(x + sbase + s*1024 + t*64 + 16*m + 4*g);

  auto ldA = [&](int base_bf16, int fbidx) -> bf16x8 {
    return *(const bf16x8*)(wf + base_bf16 + fbidx*512 + lane*8);
  };

  // layernorm of R[s] -> bf16 B-frags (b0: tiles 0,1; b1: tiles 2,3)
  auto lnorm = [&](int s, const float* gp, const float* bp,
                   bf16x8& b0, bf16x8& b1) {
    float sum = 0.f, sq = 0.f;
#pragma unroll
    for (int m = 0; m < 4; ++m)
#pragma unroll
      for (int r = 0; r < 4; ++r) { float v = R[s][m][r]; sum += v; sq += v*v; }
    sum += __shfl_xor(sum, 16); sum += __shfl_xor(sum, 32);
    sq  += __shfl_xor(sq , 16); sq  += __shfl_xor(sq , 32);
    float mean = sum * 0.015625f;
    float var  = sq  * 0.015625f - mean*mean;
    float rs = __builtin_amdgcn_rsqf(var + 1e-5f);
    float xn[4][4];
#pragma unroll
    for (int m = 0; m < 4; ++m) {
      f32x4 gm = *(const f32x4*)(gp + 16*m + 4*g);
      f32x4 bm = *(const f32x4*)(bp + 16*m + 4*g);
#pragma unroll
      for (int r = 0; r < 4; ++r)
        xn[m][r] = (R[s][m][r] - mean) * rs * gm[r] + bm[r];
    }
    b0 = mkfrag(pk2(xn[0][0], xn[0][1]), pk2(xn[0][2], xn[0][3]),
                pk2(xn[1][0], xn[1][1]), pk2(xn[1][2], xn[1][3]));
    b1 = mkfrag(pk2(xn[2][0], xn[2][1]), pk2(xn[2][2], xn[2][3]),
                pk2(xn[3][0], xn[3][1]), pk2(xn[3][2], xn[3][3]));
  };

  auto attn = [&](int wq, int wk, int wv, int wp,
                  const float* bq, const float* bk, const float* bv,
                  const float* bpj, bool causal) {
    bf16x8 bx[2][2];
    lnorm(0, g1, be1, bx[0][0], bx[0][1]);
    lnorm(1, g1, be1, bx[1][0], bx[1][1]);

    // Q (kept in regs), bias as MFMA C-in
    f32x4 Q[2][4];
#pragma unroll
    for (int m = 0; m < 4; ++m) {
      bf16x8 a0 = ldA(wq, m*2+0), a1 = ldA(wq, m*2+1);
      f32x4 b4 = *(const f32x4*)(bq + 16*m + 4*g);
#pragma unroll
      for (int s = 0; s < 2; ++s)
        Q[s][m] = __builtin_amdgcn_mfma_f32_16x16x32_bf16(
            a1, bx[s][1], __builtin_amdgcn_mfma_f32_16x16x32_bf16(a0, bx[s][0], b4, 0,0,0), 0,0,0);
    }
    // K -> LDS (bf16-packed)
#pragma unroll
    for (int m = 0; m < 4; ++m) {
      bf16x8 a0 = ldA(wk, m*2+0), a1 = ldA(wk, m*2+1);
      f32x4 b4 = *(const f32x4*)(bk + 16*m + 4*g);
#pragma unroll
      for (int s = 0; s < 2; ++s) {
        f32x4 acc = __builtin_amdgcn_mfma_f32_16x16x32_bf16(
            a1, bx[s][1], __builtin_amdgcn_mfma_f32_16x16x32_bf16(a0, bx[s][0], b4, 0,0,0), 0,0,0);
        *(u32x2*)&KS[s][t][8*m + 2*g] = u32x2{pk2(acc[0], acc[1]), pk2(acc[2], acc[3])};
      }
    }
    // V -> LDS (bf16-packed)
#pragma unroll
    for (int m = 0; m < 4; ++m) {
      bf16x8 a0 = ldA(wv, m*2+0), a1 = ldA(wv, m*2+1);
      f32x4 b4 = *(const f32x4*)(bv + 16*m + 4*g);
#pragma unroll
      for (int s = 0; s < 2; ++s) {
        f32x4 acc = __builtin_amdgcn_mfma_f32_16x16x32_bf16(
            a1, bx[s][1], __builtin_amdgcn_mfma_f32_16x16x32_bf16(a0, bx[s][0], b4, 0,0,0), 0,0,0);
        *(u32x2*)&VS[s][t][8*m + 2*g] = u32x2{pk2(acc[0], acc[1]), pk2(acc[2], acc[3])};
      }
    }

    // online attention core: no stored score array
#pragma unroll
    for (int s = 0; s < 2; ++s) {
      f32x4 O[4];
#pragma unroll
      for (int mp = 0; mp < 2; ++mp) {
        f32x4 q0 = Q[s][2*mp+0], q1 = Q[s][2*mp+1];
        f32x4 acc0 = {0.f,0.f,0.f,0.f}, acc1 = {0.f,0.f,0.f,0.f};
        float den0 = 0.f, den1 = 0.f;
#pragma unroll
        for (int u = 0; u < 16; ++u) {
          u32x2 kp0 = *(const u32x2*)&KS[s][u][16*mp + 2*g];
          u32x2 kp1 = *(const u32x2*)&KS[s][u][16*mp + 8 + 2*g];
          float d0 = q0[0]*blo(kp0[0]) + q0[1]*bhi(kp0[0])
                   + q0[2]*blo(kp0[1]) + q0[3]*bhi(kp0[1]);
          float d1 = q1[0]*blo(kp1[0]) + q1[1]*bhi(kp1[0])
                   + q1[2]*blo(kp1[1]) + q1[3]*bhi(kp1[1]);
          d0 += __shfl_xor(d0, 16);
          d1 += __shfl_xor(d1, 16);
          // exp(dot/sqrt(8)); scores are tiny, no max subtraction needed
          float ex0 = (causal && (u > t)) ? 0.f : exp2f(d0 * 0.51006977f);
          float ex1 = (causal && (u > t)) ? 0.f : exp2f(d1 * 0.51006977f);
          den0 += ex0; den1 += ex1;
          u32x2 vp0 = *(const u32x2*)&VS[s][u][16*mp + 2*g];
          u32x2 vp1 = *(const u32x2*)&VS[s][u][16*mp + 8 + 2*g];
          acc0[0] += ex0*blo(vp0[0]); acc0[1] += ex0*bhi(vp0[0]);
          acc0[2] += ex0*blo(vp0[1]); acc0[3] += ex0*bhi(vp0[1]);
          acc1[0] += ex1*blo(vp1[0]); acc1[1] += ex1*bhi(vp1[0]);
          acc1[2] += ex1*blo(vp1[1]); acc1[3] += ex1*bhi(vp1[1]);
        }
        float rd0 = __builtin_amdgcn_rcpf(den0), rd1 = __builtin_amdgcn_rcpf(den1);
#pragma unroll
        for (int r = 0; r < 4; ++r) { O[2*mp+0][r] = acc0[r]*rd0; O[2*mp+1][r] = acc1[r]*rd1; }
      }
      bx[s][0] = mkfrag(pk2(O[0][0], O[0][1]), pk2(O[0][2], O[0][3]),
                        pk2(O[1][0], O[1][1]), pk2(O[1][2], O[1][3]));
      bx[s][1] = mkfrag(pk2(O[2][0], O[2][1]), pk2(O[2][2], O[2][3]),
                        pk2(O[3][0], O[3][1]), pk2(O[3][2], O[3][3]));
    }
    // output projection + residual: accumulate straight into R
#pragma unroll
    for (int m = 0; m < 4; ++m) {
      bf16x8 a0 = ldA(wp, m*2+0), a1 = ldA(wp, m*2+1);
      f32x4 b4 = *(const f32x4*)(bpj + 16*m + 4*g);
#pragma unroll
      for (int s = 0; s < 2; ++s) {
        R[s][m] = __builtin_amdgcn_mfma_f32_16x16x32_bf16(
            a1, bx[s][1], __builtin_amdgcn_mfma_f32_16x16x32_bf16(a0, bx[s][0], R[s][m], 0,0,0), 0,0,0);
#pragma unroll
        for (int r = 0; r < 4; ++r) R[s][m][r] += b4[r];
      }
    }
  };

  auto ffn = [&]() {
    bf16x8 bx[2][2];
    lnorm(0, g2, be2, bx[0][0], bx[0][1]);
    lnorm(1, g2, be2, bx[1][0], bx[1][1]);
#pragma unroll
    for (int qt = 0; qt < 4; ++qt) {       // hidden in quarters of 64
#pragma unroll
      for (int q2 = 0; q2 < 2; ++q2) {     // 32-wide k-blocks
        f32x4 h[2][2];
#pragma unroll
        for (int mt2 = 0; mt2 < 2; ++mt2) {
          int ht = qt*4 + 2*q2 + mt2;
          bf16x8 a0 = ldA(OFF_F1, ht*2+0), a1 = ldA(OFF_F1, ht*2+1);
          f32x4 b4 = *(const f32x4*)(fb1 + 16*ht + 4*g);
#pragma unroll
          for (int s = 0; s < 2; ++s) {
            f32x4 acc = __builtin_amdgcn_mfma_f32_16x16x32_bf16(
                a1, bx[s][1], __builtin_amdgcn_mfma_f32_16x16x32_bf16(a0, bx[s][0], b4, 0,0,0), 0,0,0);
#pragma unroll
            for (int r = 0; r < 4; ++r) h[s][mt2][r] = gelu_f(acc[r]);
          }
        }
        bf16x8 bh0 = mkfrag(pk2(h[0][0][0], h[0][0][1]), pk2(h[0][0][2], h[0][0][3]),
                            pk2(h[0][1][0], h[0][1][1]), pk2(h[0][1][2], h[0][1][3]));
        bf16x8 bh1 = mkfrag(pk2(h[1][0][0], h[1][0][1]), pk2(h[1][0][2], h[1][0][3]),
                            pk2(h[1][1][0], h[1][1][1]), pk2(h[1][1][2], h[1][1][3]));
#pragma unroll
        for (int m = 0; m < 4; ++m) {
          bf16x8 a = ldA(OFF_F2, m*8 + qt*2 + q2);
          R[0][m] = __builtin_amdgcn_mfma_f32_16x16x32_bf16(a, bh0, R[0][m], 0,0,0);
          R[1][m] = __builtin_amdgcn_mfma_f32_16x16x32_bf16(a, bh1, R[1][m], 0,0,0);
        }
      }
    }
#pragma unroll
    for (int m = 0; m < 4; ++m) {
      f32x4 b4 = *(const f32x4*)(fb2 + 16*m + 4*g);
#pragma unroll
      for (int s = 0; s < 2; ++s)
#pragma unroll
        for (int r = 0; r < 4; ++r) R[s][m][r] += b4[r];
    }
  };

  attn(0*4096, 1*4096, 2*4096, 3*4096, ubq, ubk, ubv, ubp, false);
  ffn();
  attn(4*4096, 5*4096, 6*4096, 7*4096, mbq, mbk, mbv, mbp, true);
  ffn();

#pragma unroll
  for (int s = 0; s < 2; ++s)
#pragma unroll
    for (int m = 0; m < 4; ++m)
      *(f32x4*)(outp + sbase + s*1024 + t*64 + 16*m + 4*g) = R[s][m];
}

extern "C" void kernel_launch(void* const* d_in, const int* in_sizes, int n_in,
                              void* d_out, int out_size, void* d_ws, size_t ws_size,
                              hipStream_t stream) {
  const float* x   = (const float*)d_in[0];
  const float* uWq = (const float*)d_in[1];
  const float* ubq = (const float*)d_in[2];
  const float* uWk = (const float*)d_in[3];
  const float* ubk = (const float*)d_in[4];
  const float* uWv = (const float*)d_in[5];
  const float* ubv = (const float*)d_in[6];
  const float* uWp = (const float*)d_in[7];
  const float* ubp = (const float*)d_in[8];
  const float* mWq = (const float*)d_in[9];
  const float* mbq = (const float*)d_in[10];
  const float* mWk = (const float*)d_in[11];
  const float* mbk = (const float*)d_in[12];
  const float* mWv = (const float*)d_in[13];
  const float* mbv = (const float*)d_in[14];
  const float* mWp = (const float*)d_in[15];
  const float* mbp = (const float*)d_in[16];
  const float* fW1 = (const float*)d_in[17];
  const float* fb1 = (const float*)d_in[18];
  const float* fW2 = (const float*)d_in[19];
  const float* fb2 = (const float*)d_in[20];
  const float* g1  = (const float*)d_in[21];
  const float* be1 = (const float*)d_in[22];
  const float* g2  = (const float*)d_in[23];
  const float* be2 = (const float*)d_in[24];

  unsigned short* ws = (unsigned short*)d_ws;  // needs 131072 bytes

  prep_w<<<32, 256, 0, stream>>>(uWq, uWk, uWv, uWp, mWq, mWk, mWv, mWp,
                                 fW1, fW2, ws);
  tblock_kern<<<16384, 64, 0, stream>>>(x,
      ubq, ubk, ubv, ubp, mbq, mbk, mbv, mbp,
      fb1, fb2, g1, be1, g2, be2,
      (const unsigned short*)ws, (float*)d_out);
}